// Round 1
// baseline (760.981 us; speedup 1.0000x reference)
//
#include <hip/hip_runtime.h>
#include <hip/hip_bf16.h>

#define N_NODES 100000
#define N_EDGES 1600000
#define FEAT 32

// ---------------- CSR build ----------------

__global__ __launch_bounds__(256) void count_edges(const int* __restrict__ col,
                                                   int* __restrict__ cnt, int E) {
    int e = blockIdx.x * 256 + threadIdx.x;
    if (e < E) atomicAdd(&cnt[col[e]], 1);
}

__global__ __launch_bounds__(1024) void scan_block(const int* __restrict__ cnt,
                                                   int* __restrict__ rp,
                                                   int* __restrict__ bsum, int n) {
    __shared__ int s[1024];
    int t = threadIdx.x;
    int i = blockIdx.x * 1024 + t;
    int v = (i < n) ? cnt[i] : 0;
    s[t] = v;
    __syncthreads();
    #pragma unroll
    for (int off = 1; off < 1024; off <<= 1) {
        int x = (t >= off) ? s[t - off] : 0;
        __syncthreads();
        s[t] += x;
        __syncthreads();
    }
    if (i < n) rp[i + 1] = s[t];          // within-block inclusive scan
    if (t == 1023) bsum[blockIdx.x] = s[1023];
}

__global__ __launch_bounds__(128) void scan_sums(int* __restrict__ bsum, int nb) {
    __shared__ int s[128];
    int t = threadIdx.x;
    int v = (t < nb) ? bsum[t] : 0;
    s[t] = v;
    __syncthreads();
    #pragma unroll
    for (int off = 1; off < 128; off <<= 1) {
        int x = (t >= off) ? s[t - off] : 0;
        __syncthreads();
        s[t] += x;
        __syncthreads();
    }
    if (t < nb) bsum[t] = s[t] - v;       // exclusive
}

__global__ __launch_bounds__(1024) void scan_add(int* __restrict__ rp,
                                                 const int* __restrict__ bsum, int n) {
    int i = blockIdx.x * 1024 + threadIdx.x;
    if (i < n) rp[i + 1] += bsum[blockIdx.x];
    if (blockIdx.x == 0 && threadIdx.x == 0) rp[0] = 0;
}

__global__ __launch_bounds__(256) void copy_cursor(int* __restrict__ cursor,
                                                   const int* __restrict__ rp, int n) {
    int i = blockIdx.x * 256 + threadIdx.x;
    if (i < n) cursor[i] = rp[i];
}

__global__ __launch_bounds__(256) void fill_csr(const int* __restrict__ row,
                                                const int* __restrict__ col,
                                                int* __restrict__ cursor,
                                                int* __restrict__ csrc, int E) {
    int e = blockIdx.x * 256 + threadIdx.x;
    if (e < E) {
        int p = atomicAdd(&cursor[col[e]], 1);
        csrc[p] = row[e];
    }
}

// ---------------- per-layer kernels ----------------

// m[n] = relu(h[n] @ W + b), W is [32,32] row-major (W[k][j]).
// 32 lanes per node; lane j computes output feature j.
__global__ __launch_bounds__(256) void node_msg(const float* __restrict__ h,
                                                const float* __restrict__ W,
                                                const float* __restrict__ b,
                                                float* __restrict__ m) {
    __shared__ float Ws[32 * 32];
    __shared__ float bs[32];
    int t = threadIdx.x;
    for (int i = t; i < 1024; i += 256) Ws[i] = W[i];
    if (t < 32) bs[t] = b[t];
    __syncthreads();

    int node = blockIdx.x * 8 + (t >> 5);   // grid sized exactly: no tail
    int j = t & 31;
    float val = h[node * 32 + j];
    float acc = bs[j];
    #pragma unroll
    for (int k = 0; k < 32; k++) {
        float hk = __shfl(val, k, 32);
        acc = fmaf(hk, Ws[k * 32 + j], acc);
    }
    m[node * 32 + j] = fmaxf(acc, 0.f);
}

// agg[n] = mean over in-edges of m[src]; out[n] = act([h[n], agg[n]] @ W + b) (+h[n] if RESID)
// W is [64, OUT] row-major.
template <int OUT, bool RELU, bool RESID>
__global__ __launch_bounds__(256) void agg_out(const float* __restrict__ h,
                                               const float* __restrict__ m,
                                               const int* __restrict__ rp,
                                               const int* __restrict__ csrc,
                                               const float* __restrict__ W,
                                               const float* __restrict__ b,
                                               float* __restrict__ out) {
    __shared__ float Ws[64 * OUT];
    __shared__ float bs[OUT];
    int t = threadIdx.x;
    for (int i = t; i < 64 * OUT; i += 256) Ws[i] = W[i];
    if (t < OUT) bs[t] = b[t];
    __syncthreads();

    int node = blockIdx.x * 8 + (t >> 5);   // grid sized exactly: no tail
    int f = t & 31;

    int start = rp[node];
    int end   = rp[node + 1];
    float agg = 0.f;
    for (int p = start; p < end; p++) {
        int src = csrc[p];                  // broadcast read across half-wave
        agg += m[src * 32 + f];             // 128B coalesced gather
    }
    int deg = end - start;
    agg *= (deg > 0) ? (1.0f / (float)deg) : 1.0f;

    float hf = h[node * 32 + f];

    float acc = (f < OUT) ? bs[f] : 0.f;
    #pragma unroll
    for (int k = 0; k < 32; k++) {
        float hk = __shfl(hf, k, 32);
        float ak = __shfl(agg, k, 32);
        if (f < OUT) {
            acc = fmaf(hk, Ws[k * OUT + f], acc);
            acc = fmaf(ak, Ws[(32 + k) * OUT + f], acc);
        }
    }
    if (f < OUT) {
        if (RELU) acc = fmaxf(acc, 0.f);
        if (RESID) acc += hf;
        out[node * OUT + f] = acc;
    }
}

// ---------------- launch ----------------

extern "C" void kernel_launch(void* const* d_in, const int* in_sizes, int n_in,
                              void* d_out, int out_size, void* d_ws, size_t ws_size,
                              hipStream_t stream) {
    const float* x      = (const float*)d_in[0];
    const int*   ei     = (const int*)d_in[1];     // [2, E]: row then col
    const float* msg_w  = (const float*)d_in[3];   // [4,32,32]
    const float* msg_b  = (const float*)d_in[4];   // [4,32]
    const float* out_w  = (const float*)d_in[5];   // [3,64,32]
    const float* out_b  = (const float*)d_in[6];   // [3,32]
    const float* last_w = (const float*)d_in[7];   // [64,2]
    const float* last_b = (const float*)d_in[8];   // [2]
    float* coords = (float*)d_out;

    const int* row = ei;
    const int* col = ei + N_EDGES;

    // workspace carve-up (~45.6 MB)
    float* hA = (float*)d_ws;
    float* hB = hA + N_NODES * FEAT;
    float* m  = hB + N_NODES * FEAT;
    int* rp     = (int*)(m + N_NODES * FEAT);      // [N+1]
    int* cursor = rp + (N_NODES + 1);              // [N] (doubles as count buf)
    int* bsum   = cursor + N_NODES;                // [128]
    int* csrc   = bsum + 128;                      // [E]

    const int SCAN_BLOCKS = (N_NODES + 1023) / 1024;   // 98
    const int EDGE_BLOCKS = N_EDGES / 256;             // 6250 exact
    const int NODE_BLOCKS = N_NODES / 8;               // 12500 exact

    // --- build CSR (by destination) ---
    hipMemsetAsync(cursor, 0, N_NODES * sizeof(int), stream);
    count_edges<<<EDGE_BLOCKS, 256, 0, stream>>>(col, cursor, N_EDGES);
    scan_block<<<SCAN_BLOCKS, 1024, 0, stream>>>(cursor, rp, bsum, N_NODES);
    scan_sums<<<1, 128, 0, stream>>>(bsum, SCAN_BLOCKS);
    scan_add<<<SCAN_BLOCKS, 1024, 0, stream>>>(rp, bsum, N_NODES);
    copy_cursor<<<(N_NODES + 255) / 256, 256, 0, stream>>>(cursor, rp, N_NODES);
    fill_csr<<<EDGE_BLOCKS, 256, 0, stream>>>(row, col, cursor, csrc, N_EDGES);

    // --- layer 0: x -> hA ---
    node_msg<<<NODE_BLOCKS, 256, 0, stream>>>(x, msg_w, msg_b, m);
    agg_out<32, true, false><<<NODE_BLOCKS, 256, 0, stream>>>(
        x, m, rp, csrc, out_w, out_b, hA);

    // --- layer 1: hA -> hB (residual) ---
    node_msg<<<NODE_BLOCKS, 256, 0, stream>>>(hA, msg_w + 1024, msg_b + 32, m);
    agg_out<32, true, true><<<NODE_BLOCKS, 256, 0, stream>>>(
        hA, m, rp, csrc, out_w + 2048, out_b + 32, hB);

    // --- layer 2: hB -> hA (residual) ---
    node_msg<<<NODE_BLOCKS, 256, 0, stream>>>(hB, msg_w + 2048, msg_b + 64, m);
    agg_out<32, true, true><<<NODE_BLOCKS, 256, 0, stream>>>(
        hB, m, rp, csrc, out_w + 4096, out_b + 64, hA);

    // --- layer 3 (final): hA -> coords [N,2], no relu, no residual ---
    node_msg<<<NODE_BLOCKS, 256, 0, stream>>>(hA, msg_w + 3072, msg_b + 96, m);
    agg_out<2, false, false><<<NODE_BLOCKS, 256, 0, stream>>>(
        hA, m, rp, csrc, last_w, last_b, coords);
}

// Round 2
// 589.281 us; speedup vs baseline: 1.2914x; 1.2914x over previous
//
#include <hip/hip_runtime.h>
#include <hip/hip_fp16.h>

#define N_NODES 100000
#define N_EDGES 1600000
#define FEAT 32

// ---------------- CSR build ----------------

__global__ __launch_bounds__(256) void count_edges(const int* __restrict__ col,
                                                   int* __restrict__ cnt, int E) {
    int e = blockIdx.x * 256 + threadIdx.x;
    if (e < E) atomicAdd(&cnt[col[e]], 1);
}

__global__ __launch_bounds__(1024) void scan_block(const int* __restrict__ cnt,
                                                   int* __restrict__ rp,
                                                   int* __restrict__ bsum, int n) {
    __shared__ int s[1024];
    int t = threadIdx.x;
    int i = blockIdx.x * 1024 + t;
    int v = (i < n) ? cnt[i] : 0;
    s[t] = v;
    __syncthreads();
    #pragma unroll
    for (int off = 1; off < 1024; off <<= 1) {
        int x = (t >= off) ? s[t - off] : 0;
        __syncthreads();
        s[t] += x;
        __syncthreads();
    }
    if (i < n) rp[i + 1] = s[t];          // within-block inclusive scan
    if (t == 1023) bsum[blockIdx.x] = s[1023];
}

__global__ __launch_bounds__(128) void scan_sums(int* __restrict__ bsum, int nb) {
    __shared__ int s[128];
    int t = threadIdx.x;
    int v = (t < nb) ? bsum[t] : 0;
    s[t] = v;
    __syncthreads();
    #pragma unroll
    for (int off = 1; off < 128; off <<= 1) {
        int x = (t >= off) ? s[t - off] : 0;
        __syncthreads();
        s[t] += x;
        __syncthreads();
    }
    if (t < nb) bsum[t] = s[t] - v;       // exclusive
}

// finalizes rp and also initializes cursor = rp (fused copy_cursor)
__global__ __launch_bounds__(1024) void scan_add(int* __restrict__ rp,
                                                 int* __restrict__ cursor,
                                                 const int* __restrict__ bsum, int n) {
    int i = blockIdx.x * 1024 + threadIdx.x;
    if (i < n) {
        int v = rp[i + 1] + bsum[blockIdx.x];
        rp[i + 1] = v;
        if (i + 1 < n) cursor[i + 1] = v;
    }
    if (blockIdx.x == 0 && threadIdx.x == 0) { rp[0] = 0; cursor[0] = 0; }
}

__global__ __launch_bounds__(256) void fill_csr(const int* __restrict__ row,
                                                const int* __restrict__ col,
                                                int* __restrict__ cursor,
                                                int* __restrict__ csrc, int E) {
    int e = blockIdx.x * 256 + threadIdx.x;
    if (e < E) {
        int p = atomicAdd(&cursor[col[e]], 1);
        csrc[p] = row[e];
    }
}

// ---------------- per-layer kernels ----------------

// m[n] = relu(h[n] @ W + b) stored as fp16. W is [32,32] row-major.
// 32 lanes per node; lane j computes output feature j.
__global__ __launch_bounds__(256) void node_msg(const float* __restrict__ h,
                                                const float* __restrict__ W,
                                                const float* __restrict__ b,
                                                __half* __restrict__ m) {
    __shared__ float Ws[32 * 32];
    __shared__ float bs[32];
    int t = threadIdx.x;
    for (int i = t; i < 1024; i += 256) Ws[i] = W[i];
    if (t < 32) bs[t] = b[t];
    __syncthreads();

    int node = blockIdx.x * 8 + (t >> 5);   // grid sized exactly: no tail
    int j = t & 31;
    float val = h[node * 32 + j];
    float acc = bs[j];
    #pragma unroll
    for (int k = 0; k < 32; k++) {
        float hk = __shfl(val, k, 32);
        acc = fmaf(hk, Ws[k * 32 + j], acc);
    }
    m[node * 32 + j] = __float2half(fmaxf(acc, 0.f));
}

// agg[n] = mean over in-edges of m[src]; out[n] = act([h[n], agg[n]] @ W + b) (+h[n] if RESID)
// W is [64, OUT] row-major. Half-wave (32 lanes) per node, lane = feature.
template <int OUT, bool RELU, bool RESID>
__global__ __launch_bounds__(256) void agg_out(const float* __restrict__ h,
                                               const __half* __restrict__ m,
                                               const int* __restrict__ rp,
                                               const int* __restrict__ csrc,
                                               const float* __restrict__ W,
                                               const float* __restrict__ b,
                                               float* __restrict__ out) {
    __shared__ float Ws[64 * OUT];
    __shared__ float bs[OUT];
    int t = threadIdx.x;
    for (int i = t; i < 64 * OUT; i += 256) Ws[i] = W[i];
    if (t < OUT) bs[t] = b[t];
    __syncthreads();

    int node = blockIdx.x * 8 + (t >> 5);   // grid sized exactly: no tail
    int f = t & 31;

    int start = rp[node];
    int end   = rp[node + 1];
    int deg   = end - start;

    // gather-mean with coalesced index load + shfl broadcast + 4-way MLP
    float a0 = 0.f, a1 = 0.f, a2 = 0.f, a3 = 0.f;
    int p = start;
    while (p < end) {
        int nrem = end - p;
        int cnt = (nrem < 32) ? nrem : 32;
        int src_f = (f < cnt) ? csrc[p + f] : 0;   // one coalesced load / chunk
        int k = 0;
        for (; k + 4 <= cnt; k += 4) {
            int s0 = __shfl(src_f, k,     32);
            int s1 = __shfl(src_f, k + 1, 32);
            int s2 = __shfl(src_f, k + 2, 32);
            int s3 = __shfl(src_f, k + 3, 32);
            a0 += __half2float(m[s0 * 32 + f]);
            a1 += __half2float(m[s1 * 32 + f]);
            a2 += __half2float(m[s2 * 32 + f]);
            a3 += __half2float(m[s3 * 32 + f]);
        }
        for (; k < cnt; k++) {
            int s = __shfl(src_f, k, 32);
            a0 += __half2float(m[s * 32 + f]);
        }
        p += cnt;
    }
    float agg = (a0 + a1) + (a2 + a3);
    agg *= (deg > 0) ? (1.0f / (float)deg) : 1.0f;

    float hf = h[node * 32 + f];

    float acc = (f < OUT) ? bs[f] : 0.f;
    #pragma unroll
    for (int k = 0; k < 32; k++) {
        float hk = __shfl(hf, k, 32);
        float ak = __shfl(agg, k, 32);
        if (f < OUT) {
            acc = fmaf(hk, Ws[k * OUT + f], acc);
            acc = fmaf(ak, Ws[(32 + k) * OUT + f], acc);
        }
    }
    if (f < OUT) {
        if (RELU) acc = fmaxf(acc, 0.f);
        if (RESID) acc += hf;
        out[node * OUT + f] = acc;
    }
}

// ---------------- launch ----------------

extern "C" void kernel_launch(void* const* d_in, const int* in_sizes, int n_in,
                              void* d_out, int out_size, void* d_ws, size_t ws_size,
                              hipStream_t stream) {
    const float* x      = (const float*)d_in[0];
    const int*   ei     = (const int*)d_in[1];     // [2, E]: row then col
    const float* msg_w  = (const float*)d_in[3];   // [4,32,32]
    const float* msg_b  = (const float*)d_in[4];   // [4,32]
    const float* out_w  = (const float*)d_in[5];   // [3,64,32]
    const float* out_b  = (const float*)d_in[6];   // [3,32]
    const float* last_w = (const float*)d_in[7];   // [64,2]
    const float* last_b = (const float*)d_in[8];   // [2]
    float* coords = (float*)d_out;

    const int* row = ei;
    const int* col = ei + N_EDGES;

    // workspace carve-up (~39 MB)
    float* hA = (float*)d_ws;                       // 12.8 MB
    float* hB = hA + N_NODES * FEAT;                // 12.8 MB
    __half* m = (__half*)(hB + N_NODES * FEAT);     // 6.4 MB
    int* rp     = (int*)(m + N_NODES * FEAT);       // [N+1]
    int* cursor = rp + (N_NODES + 1);               // [N] (doubles as count buf)
    int* bsum   = cursor + N_NODES;                 // [128]
    int* csrc   = bsum + 128;                       // [E] 6.4 MB

    const int SCAN_BLOCKS = (N_NODES + 1023) / 1024;   // 98
    const int EDGE_BLOCKS = N_EDGES / 256;             // 6250 exact
    const int NODE_BLOCKS = N_NODES / 8;               // 12500 exact

    // --- build CSR (by destination) ---
    hipMemsetAsync(cursor, 0, N_NODES * sizeof(int), stream);
    count_edges<<<EDGE_BLOCKS, 256, 0, stream>>>(col, cursor, N_EDGES);
    scan_block<<<SCAN_BLOCKS, 1024, 0, stream>>>(cursor, rp, bsum, N_NODES);
    scan_sums<<<1, 128, 0, stream>>>(bsum, SCAN_BLOCKS);
    scan_add<<<SCAN_BLOCKS, 1024, 0, stream>>>(rp, cursor, bsum, N_NODES);
    fill_csr<<<EDGE_BLOCKS, 256, 0, stream>>>(row, col, cursor, csrc, N_EDGES);

    // --- layer 0: x -> hA ---
    node_msg<<<NODE_BLOCKS, 256, 0, stream>>>(x, msg_w, msg_b, m);
    agg_out<32, true, false><<<NODE_BLOCKS, 256, 0, stream>>>(
        x, m, rp, csrc, out_w, out_b, hA);

    // --- layer 1: hA -> hB (residual) ---
    node_msg<<<NODE_BLOCKS, 256, 0, stream>>>(hA, msg_w + 1024, msg_b + 32, m);
    agg_out<32, true, true><<<NODE_BLOCKS, 256, 0, stream>>>(
        hA, m, rp, csrc, out_w + 2048, out_b + 32, hB);

    // --- layer 2: hB -> hA (residual) ---
    node_msg<<<NODE_BLOCKS, 256, 0, stream>>>(hB, msg_w + 2048, msg_b + 64, m);
    agg_out<32, true, true><<<NODE_BLOCKS, 256, 0, stream>>>(
        hB, m, rp, csrc, out_w + 4096, out_b + 64, hA);

    // --- layer 3 (final): hA -> coords [N,2], no relu, no residual ---
    node_msg<<<NODE_BLOCKS, 256, 0, stream>>>(hA, msg_w + 3072, msg_b + 96, m);
    agg_out<2, false, false><<<NODE_BLOCKS, 256, 0, stream>>>(
        hA, m, rp, csrc, last_w, last_b, coords);
}

// Round 3
// 424.536 us; speedup vs baseline: 1.7925x; 1.3881x over previous
//
#include <hip/hip_runtime.h>
#include <hip/hip_fp16.h>

#define N_NODES 100000
#define N_EDGES 1600000
#define FEAT 32

#define BUCKET_SHIFT 8                       // 256 nodes per bucket
#define NB 391                               // ceil(100000/256)
#define P1_BLOCKS 256
#define EPB (N_EDGES / P1_BLOCKS)            // 6250 edges per pass-1 block
#define SCAN_N (NB * P1_BLOCKS)              // 100096

// ---------------- CSR build: 2-pass LDS-binned counting sort ----------------

// Pass 1a: per-block LDS histogram over coarse buckets (no global atomics).
__global__ __launch_bounds__(256) void bin_count(const int* __restrict__ col,
                                                 int* __restrict__ hist) {
    __shared__ int h[NB];
    int t = threadIdx.x;
    for (int i = t; i < NB; i += 256) h[i] = 0;
    __syncthreads();
    int base = blockIdx.x * EPB;
    for (int i = t; i < EPB; i += 256)
        atomicAdd(&h[col[base + i] >> BUCKET_SHIFT], 1);
    __syncthreads();
    for (int i = t; i < NB; i += 256)
        hist[i * P1_BLOCKS + blockIdx.x] = h[i];     // bucket-major
}

__global__ __launch_bounds__(1024) void scan_block(const int* __restrict__ cnt,
                                                   int* __restrict__ ex,
                                                   int* __restrict__ bsum, int n) {
    __shared__ int s[1024];
    int t = threadIdx.x;
    int i = blockIdx.x * 1024 + t;
    int v = (i < n) ? cnt[i] : 0;
    s[t] = v;
    __syncthreads();
    #pragma unroll
    for (int off = 1; off < 1024; off <<= 1) {
        int x = (t >= off) ? s[t - off] : 0;
        __syncthreads();
        s[t] += x;
        __syncthreads();
    }
    if (i < n) ex[i + 1] = s[t];          // within-block inclusive scan
    if (t == 1023) bsum[blockIdx.x] = s[1023];
}

__global__ __launch_bounds__(128) void scan_sums(int* __restrict__ bsum, int nb) {
    __shared__ int s[128];
    int t = threadIdx.x;
    int v = (t < nb) ? bsum[t] : 0;
    s[t] = v;
    __syncthreads();
    #pragma unroll
    for (int off = 1; off < 128; off <<= 1) {
        int x = (t >= off) ? s[t - off] : 0;
        __syncthreads();
        s[t] += x;
        __syncthreads();
    }
    if (t < nb) bsum[t] = s[t] - v;       // exclusive
}

__global__ __launch_bounds__(1024) void scan_add(int* __restrict__ ex,
                                                 const int* __restrict__ bsum, int n) {
    int i = blockIdx.x * 1024 + threadIdx.x;
    if (i < n) ex[i + 1] += bsum[blockIdx.x];
    if (blockIdx.x == 0 && threadIdx.x == 0) ex[0] = 0;
}

// Pass 1c: scatter packed (col,row) records into bucket-ordered array.
// Each block's writes per bucket are contiguous runs (LDS cursors, no global atomics).
__global__ __launch_bounds__(256) void bin_scatter(const int* __restrict__ row,
                                                   const int* __restrict__ col,
                                                   const int* __restrict__ hoff,
                                                   long long* __restrict__ binned) {
    __shared__ int cur[NB];
    int t = threadIdx.x;
    for (int i = t; i < NB; i += 256) cur[i] = hoff[i * P1_BLOCKS + blockIdx.x];
    __syncthreads();
    int base = blockIdx.x * EPB;
    for (int i = t; i < EPB; i += 256) {
        int c = col[base + i];
        int r = row[base + i];
        int p = atomicAdd(&cur[c >> BUCKET_SHIFT], 1);
        binned[p] = ((long long)c << 32) | (unsigned int)r;
    }
}

// Pass 2: one block per bucket; each block exclusively owns a contiguous csrc
// window -> no cross-XCD line bouncing. Writes rp sequentially.
__global__ __launch_bounds__(256) void bucket_sort(const long long* __restrict__ binned,
                                                   const int* __restrict__ hoff,
                                                   int* __restrict__ rp,
                                                   int* __restrict__ csrc) {
    __shared__ int h[256];
    int b = blockIdx.x, t = threadIdx.x;
    int bstart = hoff[b * P1_BLOCKS];
    int bend   = hoff[(b + 1) * P1_BLOCKS];
    h[t] = 0;
    __syncthreads();
    for (int p = bstart + t; p < bend; p += 256)
        atomicAdd(&h[(int)(binned[p] >> 32) & 255], 1);
    __syncthreads();
    int deg = h[t];
    #pragma unroll
    for (int off = 1; off < 256; off <<= 1) {       // inclusive scan
        int x = (t >= off) ? h[t - off] : 0;
        __syncthreads();
        h[t] += x;
        __syncthreads();
    }
    int mystart = bstart + h[t] - deg;
    int node = (b << BUCKET_SHIFT) + t;
    if (node < N_NODES) rp[node] = mystart;
    if (b == NB - 1 && t == 0) rp[N_NODES] = N_EDGES;
    __syncthreads();
    h[t] = mystart;                                  // cursor
    __syncthreads();
    for (int p = bstart + t; p < bend; p += 256) {
        long long rec = binned[p];
        int local = (int)(rec >> 32) & 255;
        int pos = atomicAdd(&h[local], 1);
        csrc[pos] = (int)rec;
    }
}

// ---------------- per-layer kernels ----------------

// m[n] = relu(h[n] @ W + b) stored as fp16. W is [32,32] row-major.
__global__ __launch_bounds__(256) void node_msg(const float* __restrict__ h,
                                                const float* __restrict__ W,
                                                const float* __restrict__ b,
                                                __half* __restrict__ m) {
    __shared__ float Ws[32 * 32];
    __shared__ float bs[32];
    int t = threadIdx.x;
    for (int i = t; i < 1024; i += 256) Ws[i] = W[i];
    if (t < 32) bs[t] = b[t];
    __syncthreads();

    int node = blockIdx.x * 8 + (t >> 5);   // grid sized exactly: no tail
    int j = t & 31;
    float val = h[node * 32 + j];
    float acc = bs[j];
    #pragma unroll
    for (int k = 0; k < 32; k++) {
        float hk = __shfl(val, k, 32);
        acc = fmaf(hk, Ws[k * 32 + j], acc);
    }
    m[node * 32 + j] = __float2half(fmaxf(acc, 0.f));
}

// agg[n] = mean over in-edges of m[src]; out[n] = act([h[n], agg[n]] @ W + b) (+h if RESID)
template <int OUT, bool RELU, bool RESID>
__global__ __launch_bounds__(256) void agg_out(const float* __restrict__ h,
                                               const __half* __restrict__ m,
                                               const int* __restrict__ rp,
                                               const int* __restrict__ csrc,
                                               const float* __restrict__ W,
                                               const float* __restrict__ b,
                                               float* __restrict__ out) {
    __shared__ float Ws[64 * OUT];
    __shared__ float bs[OUT];
    int t = threadIdx.x;
    for (int i = t; i < 64 * OUT; i += 256) Ws[i] = W[i];
    if (t < OUT) bs[t] = b[t];
    __syncthreads();

    int node = blockIdx.x * 8 + (t >> 5);   // grid sized exactly: no tail
    int f = t & 31;

    int start = rp[node];
    int end   = rp[node + 1];
    int deg   = end - start;

    float a0 = 0.f, a1 = 0.f, a2 = 0.f, a3 = 0.f;
    int p = start;
    while (p < end) {
        int nrem = end - p;
        int cnt = (nrem < 32) ? nrem : 32;
        int src_f = (f < cnt) ? csrc[p + f] : 0;   // one coalesced load / chunk
        int k = 0;
        for (; k + 4 <= cnt; k += 4) {
            int s0 = __shfl(src_f, k,     32);
            int s1 = __shfl(src_f, k + 1, 32);
            int s2 = __shfl(src_f, k + 2, 32);
            int s3 = __shfl(src_f, k + 3, 32);
            a0 += __half2float(m[s0 * 32 + f]);
            a1 += __half2float(m[s1 * 32 + f]);
            a2 += __half2float(m[s2 * 32 + f]);
            a3 += __half2float(m[s3 * 32 + f]);
        }
        for (; k < cnt; k++) {
            int s = __shfl(src_f, k, 32);
            a0 += __half2float(m[s * 32 + f]);
        }
        p += cnt;
    }
    float agg = (a0 + a1) + (a2 + a3);
    agg *= (deg > 0) ? (1.0f / (float)deg) : 1.0f;

    float hf = h[node * 32 + f];

    float acc = (f < OUT) ? bs[f] : 0.f;
    #pragma unroll
    for (int k = 0; k < 32; k++) {
        float hk = __shfl(hf, k, 32);
        float ak = __shfl(agg, k, 32);
        if (f < OUT) {
            acc = fmaf(hk, Ws[k * OUT + f], acc);
            acc = fmaf(ak, Ws[(32 + k) * OUT + f], acc);
        }
    }
    if (f < OUT) {
        if (RELU) acc = fmaxf(acc, 0.f);
        if (RESID) acc += hf;
        out[node * OUT + f] = acc;
    }
}

// ---------------- launch ----------------

extern "C" void kernel_launch(void* const* d_in, const int* in_sizes, int n_in,
                              void* d_out, int out_size, void* d_ws, size_t ws_size,
                              hipStream_t stream) {
    const float* x      = (const float*)d_in[0];
    const int*   ei     = (const int*)d_in[1];     // [2, E]: row then col
    const float* msg_w  = (const float*)d_in[3];   // [4,32,32]
    const float* msg_b  = (const float*)d_in[4];   // [4,32]
    const float* out_w  = (const float*)d_in[5];   // [3,64,32]
    const float* out_b  = (const float*)d_in[6];   // [3,32]
    const float* last_w = (const float*)d_in[7];   // [64,2]
    const float* last_b = (const float*)d_in[8];   // [2]
    float* coords = (float*)d_out;

    const int* row = ei;
    const int* col = ei + N_EDGES;

    // workspace carve-up (~40 MB); binned overlaps hA/hB (dead until layer 0)
    float* hA  = (float*)d_ws;                      // 12.8 MB
    float* hB  = hA + N_NODES * FEAT;               // 12.8 MB
    __half* m  = (__half*)(hB + N_NODES * FEAT);    // 6.4 MB
    int* rp    = (int*)(m + N_NODES * FEAT);        // [N+1]
    int* hoff  = rp + (N_NODES + 1);                // [SCAN_N+1]
    int* bsum  = hoff + (SCAN_N + 1);               // [128]
    int* hist  = bsum + 128;                        // [SCAN_N]
    int* csrc  = hist + SCAN_N;                     // [E] 6.4 MB
    long long* binned = (long long*)hA;             // [E] 12.8 MB (overlap)

    const int SCAN_BLOCKS = (SCAN_N + 1023) / 1024;    // 98
    const int NODE_BLOCKS = N_NODES / 8;               // 12500 exact

    // --- build CSR (by destination), no global atomics ---
    bin_count<<<P1_BLOCKS, 256, 0, stream>>>(col, hist);
    scan_block<<<SCAN_BLOCKS, 1024, 0, stream>>>(hist, hoff, bsum, SCAN_N);
    scan_sums<<<1, 128, 0, stream>>>(bsum, SCAN_BLOCKS);
    scan_add<<<SCAN_BLOCKS, 1024, 0, stream>>>(hoff, bsum, SCAN_N);
    bin_scatter<<<P1_BLOCKS, 256, 0, stream>>>(row, col, hoff, binned);
    bucket_sort<<<NB, 256, 0, stream>>>(binned, hoff, rp, csrc);

    // --- layer 0: x -> hA ---
    node_msg<<<NODE_BLOCKS, 256, 0, stream>>>(x, msg_w, msg_b, m);
    agg_out<32, true, false><<<NODE_BLOCKS, 256, 0, stream>>>(
        x, m, rp, csrc, out_w, out_b, hA);

    // --- layer 1: hA -> hB (residual) ---
    node_msg<<<NODE_BLOCKS, 256, 0, stream>>>(hA, msg_w + 1024, msg_b + 32, m);
    agg_out<32, true, true><<<NODE_BLOCKS, 256, 0, stream>>>(
        hA, m, rp, csrc, out_w + 2048, out_b + 32, hB);

    // --- layer 2: hB -> hA (residual) ---
    node_msg<<<NODE_BLOCKS, 256, 0, stream>>>(hB, msg_w + 2048, msg_b + 64, m);
    agg_out<32, true, true><<<NODE_BLOCKS, 256, 0, stream>>>(
        hB, m, rp, csrc, out_w + 4096, out_b + 64, hA);

    // --- layer 3 (final): hA -> coords [N,2], no relu, no residual ---
    node_msg<<<NODE_BLOCKS, 256, 0, stream>>>(hA, msg_w + 3072, msg_b + 96, m);
    agg_out<2, false, false><<<NODE_BLOCKS, 256, 0, stream>>>(
        hA, m, rp, csrc, last_w, last_b, coords);
}